// Round 2
// baseline (1246.917 us; speedup 1.0000x reference)
//
#include <hip/hip_runtime.h>
#include <hip/hip_bf16.h>

#define NTOK 4096
#define DDIM 1024
#define NEXP 8
#define FDIM 4096

typedef __attribute__((ext_vector_type(4))) float f32x4;
typedef __attribute__((ext_vector_type(8))) short bf16x8;
typedef __attribute__((ext_vector_type(8))) unsigned short u16x8;

// ---------------- init: zero atomically-accumulated outputs & scratch ----------------
__global__ __launch_bounds__(64) void init_kernel(float* __restrict__ out_tail,
                                                  int* __restrict__ expert_count) {
    int t = threadIdx.x;
    if (t < 17) out_tail[t] = 0.0f;          // counts[8], prob_sum[8], n_dropped
    if (t < NEXP) expert_count[t] = 0;
}

// ---------------- routing: logits -> softmax -> argmax; build buckets; xs=bf16(x*pmax) ----
__global__ __launch_bounds__(64) void route_kernel(
    const float* __restrict__ x,         // [NTOK, D]
    const float* __restrict__ w_switch,  // [D, E]
    const float* __restrict__ b_switch,  // [E]
    __hip_bfloat16* __restrict__ xs,     // [NTOK, D]
    int* __restrict__ bucket,            // [E, NTOK]
    int* __restrict__ expert_count,      // [E]
    float* __restrict__ counts_out,      // [E]  (d_out tail)
    float* __restrict__ prob_out)        // [E]  (d_out tail)
{
    const int n = blockIdx.x;
    const int lane = threadIdx.x;
    const float* xr = x + (size_t)n * DDIM;

    float acc[NEXP];
#pragma unroll
    for (int e = 0; e < NEXP; e++) acc[e] = 0.0f;

    for (int i = 0; i < DDIM / 64; i++) {
        int d = lane + i * 64;
        float xv = xr[d];
        const float4* wr = (const float4*)(w_switch + (size_t)d * NEXP);
        float4 w0 = wr[0], w1 = wr[1];
        acc[0] += xv * w0.x; acc[1] += xv * w0.y;
        acc[2] += xv * w0.z; acc[3] += xv * w0.w;
        acc[4] += xv * w1.x; acc[5] += xv * w1.y;
        acc[6] += xv * w1.z; acc[7] += xv * w1.w;
    }
    // full butterfly reduce: all lanes end with the complete dot products
#pragma unroll
    for (int e = 0; e < NEXP; e++) {
        float v = acc[e];
#pragma unroll
        for (int off = 32; off > 0; off >>= 1) v += __shfl_xor(v, off, 64);
        acc[e] = v;
    }
    float logit[NEXP];
    float mx = -1e30f;
#pragma unroll
    for (int e = 0; e < NEXP; e++) {
        logit[e] = acc[e] + b_switch[e];
        mx = fmaxf(mx, logit[e]);
    }
    float sum = 0.0f;
#pragma unroll
    for (int e = 0; e < NEXP; e++) { logit[e] = __expf(logit[e] - mx); sum += logit[e]; }
    float inv = 1.0f / sum;
    float pmax = -1.0f; int amax = 0;
#pragma unroll
    for (int e = 0; e < NEXP; e++) {
        float p = logit[e] * inv;
        logit[e] = p;
        if (p > pmax) { pmax = p; amax = e; }
    }
    if (lane == 0) {
        atomicAdd(&counts_out[amax], 1.0f);
#pragma unroll
        for (int e = 0; e < NEXP; e++) atomicAdd(&prob_out[e], logit[e]);
        int pos = atomicAdd(&expert_count[amax], 1);
        bucket[amax * NTOK + pos] = n;
    }
    // write scaled bf16 token row
    for (int i = 0; i < DDIM / 64; i++) {
        int d = lane + i * 64;
        xs[(size_t)n * DDIM + d] = __float2bfloat16(xr[d] * pmax);
    }
}

// ---------------- grouped GEMM: C[tok, n] = A[tok, :] @ Bw[e] + bias ----------------
// MODE 0: out = bf16(relu(v))  into h [NTOK, NN]
// MODE 1: out = float v        into d_out [NTOK, NN]
template <int MODE, int K, int NN>
__global__ __launch_bounds__(256) void gemm_kernel(
    const __hip_bfloat16* __restrict__ A,  // [NTOK, K]
    const float* __restrict__ Bw,          // [E, K, NN] fp32
    const float* __restrict__ bias,        // [E, NN]
    const int* __restrict__ bucket,        // [E, NTOK]
    const int* __restrict__ expert_count,  // [E]
    void* __restrict__ Out)
{
    const int e = blockIdx.z;
    const int cnt = expert_count[e];
    const int m0 = blockIdx.y * 64;
    if (m0 >= cnt) return;
    const int n0 = blockIdx.x * 64;

    const float* B = Bw + (size_t)e * K * NN;
    const float* be = bias + (size_t)e * NN;
    const int* buck = bucket + (size_t)e * NTOK;

    __shared__ __hip_bfloat16 Asm[64 * 40];
    __shared__ __hip_bfloat16 Bsm[64 * 40];
    __shared__ int toks[64];

    const int tid = threadIdx.x;
    if (tid < 64) {
        int r = m0 + tid;
        toks[tid] = buck[r < cnt ? r : (cnt - 1)];
    }
    __syncthreads();

    const int lane = tid & 63;
    const int wave = tid >> 6;
    const int quad = lane >> 4;
    const int l15 = lane & 15;

    f32x4 acc[4];
#pragma unroll
    for (int t = 0; t < 4; t++) acc[t] = (f32x4){0.f, 0.f, 0.f, 0.f};

    const int arow = tid >> 2;        // 0..63  (row of A tile)
    const int acol = (tid & 3) * 8;   // 0,8,16,24 (8 bf16 = 16B per thread)
    const __hip_bfloat16* a_src = A + (size_t)toks[arow] * K + acol;

    for (int k0 = 0; k0 < K; k0 += 32) {
        // stage A tile: 64 rows x 32 k (bf16), 16B (8 elems) per thread
        *(u16x8*)&Asm[arow * 40 + acol] = *(const u16x8*)(a_src + k0);
        // stage B tile: 32 k x 64 n fp32 -> bf16, transposed to [n][k]
#pragma unroll
        for (int rep = 0; rep < 2; rep++) {
            int idx = tid + rep * 256;     // 0..511
            int kk = idx >> 4;             // 0..31
            int nn4 = (idx & 15) * 4;      // 0..60
            float4 v = *(const float4*)&B[(size_t)(k0 + kk) * NN + n0 + nn4];
            Bsm[(nn4 + 0) * 40 + kk] = __float2bfloat16(v.x);
            Bsm[(nn4 + 1) * 40 + kk] = __float2bfloat16(v.y);
            Bsm[(nn4 + 2) * 40 + kk] = __float2bfloat16(v.z);
            Bsm[(nn4 + 3) * 40 + kk] = __float2bfloat16(v.w);
        }
        __syncthreads();

        bf16x8 a = *(bf16x8*)&Asm[(wave * 16 + l15) * 40 + quad * 8];
#pragma unroll
        for (int t = 0; t < 4; t++) {
            bf16x8 b = *(bf16x8*)&Bsm[(t * 16 + l15) * 40 + quad * 8];
            acc[t] = __builtin_amdgcn_mfma_f32_16x16x32_bf16(a, b, acc[t], 0, 0, 0);
        }
        __syncthreads();
    }

    // epilogue: C row = wave*16 + quad*4 + r, col = n0 + t*16 + l15
#pragma unroll
    for (int t = 0; t < 4; t++) {
        int col = n0 + t * 16 + l15;
        float bv = be[col];
#pragma unroll
        for (int r = 0; r < 4; r++) {
            int row = wave * 16 + quad * 4 + r;
            if (m0 + row < cnt) {
                int tok = toks[row];
                float v = acc[t][r] + bv;
                if (MODE == 0) {
                    v = fmaxf(v, 0.0f);
                    ((__hip_bfloat16*)Out)[(size_t)tok * NN + col] = __float2bfloat16(v);
                } else {
                    ((float*)Out)[(size_t)tok * NN + col] = v;
                }
            }
        }
    }
}

extern "C" void kernel_launch(void* const* d_in, const int* in_sizes, int n_in,
                              void* d_out, int out_size, void* d_ws, size_t ws_size,
                              hipStream_t stream) {
    const float* x        = (const float*)d_in[0];
    const float* w_switch = (const float*)d_in[1];
    const float* b_switch = (const float*)d_in[2];
    const float* w1       = (const float*)d_in[3];
    const float* b1       = (const float*)d_in[4];
    const float* w2       = (const float*)d_in[5];
    const float* b2       = (const float*)d_in[6];

    float* out = (float*)d_out;                       // [NTOK, D]
    float* out_tail = out + (size_t)NTOK * DDIM;      // counts[8], prob[8], n_dropped

    char* ws = (char*)d_ws;
    __hip_bfloat16* xs = (__hip_bfloat16*)ws;                               // 8 MB
    __hip_bfloat16* h  = (__hip_bfloat16*)(ws + (size_t)8 * 1024 * 1024);   // 32 MB
    int* bucket        = (int*)(ws + (size_t)41943040);                     // 128 KB
    int* expert_count  = (int*)(ws + (size_t)42074112);                     // 32 B

    hipLaunchKernelGGL(init_kernel, dim3(1), dim3(64), 0, stream, out_tail, expert_count);

    hipLaunchKernelGGL(route_kernel, dim3(NTOK), dim3(64), 0, stream,
                       x, w_switch, b_switch, xs, bucket, expert_count,
                       out_tail, out_tail + NEXP);

    hipLaunchKernelGGL((gemm_kernel<0, DDIM, FDIM>), dim3(FDIM / 64, NTOK / 64, NEXP),
                       dim3(256), 0, stream, xs, w1, b1, bucket, expert_count, (void*)h);

    hipLaunchKernelGGL((gemm_kernel<1, FDIM, DDIM>), dim3(DDIM / 64, NTOK / 64, NEXP),
                       dim3(256), 0, stream, h, w2, b2, bucket, expert_count, (void*)out);
}

// Round 3
// 590.248 us; speedup vs baseline: 2.1125x; 2.1125x over previous
//
#include <hip/hip_runtime.h>
#include <hip/hip_bf16.h>

#define NTOK 4096
#define DDIM 1024
#define NEXP 8
#define FDIM 4096

typedef __attribute__((ext_vector_type(4))) float f32x4;
typedef __attribute__((ext_vector_type(8))) short bf16x8;
typedef __attribute__((ext_vector_type(8))) unsigned short u16x8;

#define GLDS(g, l) __builtin_amdgcn_global_load_lds( \
    (const __attribute__((address_space(1))) unsigned int*)(g), \
    (__attribute__((address_space(3))) unsigned int*)(l), 16, 0, 0)

// ---------------- route: no global atomics. Writes xs (bf16), amax[], partial[256][16] ----
__global__ __launch_bounds__(256) void route_kernel(
    const float* __restrict__ x,         // [NTOK, D]
    const float* __restrict__ w_switch,  // [D, E]
    const float* __restrict__ b_switch,  // [E]
    __hip_bfloat16* __restrict__ xs,     // [NTOK, D]
    int* __restrict__ amax_arr,          // [NTOK]
    float* __restrict__ partial)         // [256][16]: 0..7 prob sums, 8..15 counts
{
    const int tid = threadIdx.x;
    const int wave = tid >> 6, lane = tid & 63;
    __shared__ float pr[4][16];

    float wacc[16];
#pragma unroll
    for (int j = 0; j < 16; j++) wacc[j] = 0.0f;

    for (int i = 0; i < 4; i++) {
        const int n = blockIdx.x * 16 + wave * 4 + i;
        const float4* xr = (const float4*)(x + (size_t)n * DDIM);
        float4 xv[4];
#pragma unroll
        for (int j = 0; j < 4; j++) xv[j] = xr[lane + j * 64];

        float acc[NEXP];
#pragma unroll
        for (int e = 0; e < NEXP; e++) acc[e] = 0.0f;
#pragma unroll
        for (int j = 0; j < 4; j++) {
            const int dbase = (lane + j * 64) * 4;
#pragma unroll
            for (int c = 0; c < 4; c++) {
                const float4* wr = (const float4*)(w_switch + (size_t)(dbase + c) * NEXP);
                float4 w0 = wr[0], w1 = wr[1];
                float xvc = ((const float*)&xv[j])[c];
                acc[0] += xvc * w0.x; acc[1] += xvc * w0.y;
                acc[2] += xvc * w0.z; acc[3] += xvc * w0.w;
                acc[4] += xvc * w1.x; acc[5] += xvc * w1.y;
                acc[6] += xvc * w1.z; acc[7] += xvc * w1.w;
            }
        }
#pragma unroll
        for (int e = 0; e < NEXP; e++) {
            float v = acc[e];
#pragma unroll
            for (int off = 32; off > 0; off >>= 1) v += __shfl_xor(v, off, 64);
            acc[e] = v;
        }
        float mx = -1e30f;
#pragma unroll
        for (int e = 0; e < NEXP; e++) {
            acc[e] += b_switch[e];
            mx = fmaxf(mx, acc[e]);
        }
        float sum = 0.0f;
#pragma unroll
        for (int e = 0; e < NEXP; e++) { acc[e] = __expf(acc[e] - mx); sum += acc[e]; }
        float inv = 1.0f / sum;
        float pmax = -1.0f; int amax = 0;
#pragma unroll
        for (int e = 0; e < NEXP; e++) {
            float p = acc[e] * inv;
            acc[e] = p;
            if (p > pmax) { pmax = p; amax = e; }
        }
#pragma unroll
        for (int e = 0; e < NEXP; e++) {
            wacc[e] += acc[e];
            wacc[8 + e] += (amax == e) ? 1.0f : 0.0f;
        }
        if (lane == 0) amax_arr[n] = amax;
        // write scaled bf16 row: 4 x 8B stores per lane
#pragma unroll
        for (int j = 0; j < 4; j++) {
            ushort4 pk;
            __hip_bfloat16* pp = (__hip_bfloat16*)&pk;
            pp[0] = __float2bfloat16(xv[j].x * pmax);
            pp[1] = __float2bfloat16(xv[j].y * pmax);
            pp[2] = __float2bfloat16(xv[j].z * pmax);
            pp[3] = __float2bfloat16(xv[j].w * pmax);
            *(ushort4*)(xs + (size_t)n * DDIM + (lane + j * 64) * 4) = pk;
        }
    }
    if (lane == 0) {
#pragma unroll
        for (int j = 0; j < 16; j++) pr[wave][j] = wacc[j];
    }
    __syncthreads();
    if (tid < 16)
        partial[blockIdx.x * 16 + tid] = pr[0][tid] + pr[1][tid] + pr[2][tid] + pr[3][tid];
}

// ---------------- finalize: reduce partials -> out_tail (counts[8], prob[8], n_dropped) ----
__global__ __launch_bounds__(256) void finalize_kernel(
    const float* __restrict__ partial, float* __restrict__ out_tail)
{
    __shared__ float red[16][16];
    const int j = threadIdx.x & 15, g = threadIdx.x >> 4;
    float s = 0.0f;
    for (int k = 0; k < 16; k++) s += partial[(size_t)(g + k * 16) * 16 + j];
    red[g][j] = s;
    __syncthreads();
    if (threadIdx.x < 16) {
        float t = 0.0f;
        for (int k = 0; k < 16; k++) t += red[k][threadIdx.x];
        int dst = (threadIdx.x < 8) ? (8 + threadIdx.x) : (threadIdx.x - 8);
        out_tail[dst] = t;   // j<8 are prob sums -> slots 8..15; j>=8 are counts -> 0..7
    }
    if (threadIdx.x == 16) out_tail[16] = 0.0f;  // n_dropped
}

// ---------------- bucket: per-expert token lists, ballot-aggregated, LDS counter ----------
__global__ __launch_bounds__(1024) void bucket_kernel(
    const int* __restrict__ amax_arr, int* __restrict__ bucket, int* __restrict__ ecnt)
{
    const int e = blockIdx.x;
    __shared__ int ctr;
    if (threadIdx.x == 0) ctr = 0;
    __syncthreads();
    const int lane = threadIdx.x & 63;
    for (int c = 0; c < NTOK; c += 1024) {
        int t = c + threadIdx.x;
        bool my = (amax_arr[t] == e);
        unsigned long long mask = __ballot(my);
        int cnt = __popcll(mask);
        int base = 0;
        if (lane == 0 && cnt) base = atomicAdd(&ctr, cnt);
        base = __shfl(base, 0, 64);
        if (my) {
            int rank = __popcll(mask & ((1ull << lane) - 1ull));
            bucket[e * NTOK + base + rank] = t;
        }
    }
    __syncthreads();
    if (threadIdx.x == 0) ecnt[e] = ctr;
}

// ---------------- transpose+convert: fp32 [E,R,C] -> bf16 [E,C,R] ----------------
template <int R, int C>
__global__ __launch_bounds__(256) void transpose_kernel(
    const float* __restrict__ in, __hip_bfloat16* __restrict__ outp)
{
    const int e = blockIdx.z;
    const int r0 = blockIdx.y * 64, c0 = blockIdx.x * 64;
    __shared__ __hip_bfloat16 t[64 * 65];   // original orientation [r][c], stride 65
    const int tid = threadIdx.x;
    const int ri = tid >> 4, c4 = (tid & 15) * 4;
    const float* src = in + ((size_t)e * R + r0) * C + c0;
#pragma unroll
    for (int rr = 0; rr < 4; rr++) {
        int r = ri + rr * 16;
        float4 v = *(const float4*)(src + (size_t)r * C + c4);
        t[r * 65 + c4 + 0] = __float2bfloat16(v.x);
        t[r * 65 + c4 + 1] = __float2bfloat16(v.y);
        t[r * 65 + c4 + 2] = __float2bfloat16(v.z);
        t[r * 65 + c4 + 3] = __float2bfloat16(v.w);
    }
    __syncthreads();
    const int co = tid >> 2, m = tid & 3;
    u16x8 v0, v1;
#pragma unroll
    for (int idx = 0; idx < 8; idx++)
        ((unsigned short*)&v0)[idx] = *(const unsigned short*)&t[(m * 16 + idx) * 65 + co];
#pragma unroll
    for (int idx = 0; idx < 8; idx++)
        ((unsigned short*)&v1)[idx] = *(const unsigned short*)&t[(m * 16 + idx + 8) * 65 + co];
    __hip_bfloat16* dst = outp + ((size_t)e * C + c0 + co) * R + r0 + m * 16;
    *(u16x8*)(dst) = v0;
    *(u16x8*)(dst + 8) = v1;
}

// ---------------- grouped GEMM, m97 structure: 128x128 tile, BK=32, global_load_lds ------
// A [NTOK,K] bf16 gathered rows; Bt [E,NN,K] bf16 (pre-transposed); out per MODE.
template <int MODE, int K, int NN>
__global__ __launch_bounds__(256) void gemm_kernel(
    const __hip_bfloat16* __restrict__ A,
    const __hip_bfloat16* __restrict__ Bt,
    const float* __restrict__ bias,        // [E, NN]
    const int* __restrict__ bucket,
    const int* __restrict__ ecnt,
    void* __restrict__ Out)
{
    const int e = blockIdx.z;
    const int cnt = ecnt[e];
    const int m0 = blockIdx.y * 128;
    if (m0 >= cnt) return;
    const int n0 = blockIdx.x * 128;

    // LDS layout: 8 groups of 16 rows; group g: 1024B, lane i -> (r=i&15, kq=i>>4)
    __shared__ __align__(16) __hip_bfloat16 Asm[128 * 32];
    __shared__ __align__(16) __hip_bfloat16 Bsm[128 * 32];
    __shared__ int toks[128];

    const int tid = threadIdx.x;
    if (tid < 128) {
        int r = m0 + tid;
        toks[tid] = bucket[e * NTOK + (r < cnt ? r : cnt - 1)];
    }
    __syncthreads();

    const int wave = tid >> 6, lane = tid & 63;
    const int r = lane & 15, kq = lane >> 4;
    const int g0 = 2 * wave, g1 = 2 * wave + 1;

    const __hip_bfloat16* pA0 = A + (size_t)toks[g0 * 16 + r] * K + kq * 8;
    const __hip_bfloat16* pA1 = A + (size_t)toks[g1 * 16 + r] * K + kq * 8;
    const __hip_bfloat16* pB0 = Bt + ((size_t)e * NN + n0 + g0 * 16 + r) * K + kq * 8;
    const __hip_bfloat16* pB1 = Bt + ((size_t)e * NN + n0 + g1 * 16 + r) * K + kq * 8;
    char* lA0 = (char*)Asm + g0 * 1024;
    char* lA1 = (char*)Asm + g1 * 1024;
    char* lB0 = (char*)Bsm + g0 * 1024;
    char* lB1 = (char*)Bsm + g1 * 1024;

    const int wm = wave & 1, wn = wave >> 1;
    f32x4 acc[4][4];
#pragma unroll
    for (int t = 0; t < 4; t++)
#pragma unroll
        for (int u = 0; u < 4; u++) acc[t][u] = (f32x4){0.f, 0.f, 0.f, 0.f};

    for (int k0 = 0; k0 < K; k0 += 32) {
        GLDS(pA0, lA0); GLDS(pA1, lA1);
        GLDS(pB0, lB0); GLDS(pB1, lB1);
        pA0 += 32; pA1 += 32; pB0 += 32; pB1 += 32;
        __syncthreads();
        bf16x8 a[4], b[4];
#pragma unroll
        for (int t = 0; t < 4; t++)
            a[t] = *(const bf16x8*)((const char*)Asm + (wm * 4 + t) * 1024 + lane * 16);
#pragma unroll
        for (int u = 0; u < 4; u++)
            b[u] = *(const bf16x8*)((const char*)Bsm + (wn * 4 + u) * 1024 + lane * 16);
#pragma unroll
        for (int t = 0; t < 4; t++)
#pragma unroll
            for (int u = 0; u < 4; u++)
                acc[t][u] = __builtin_amdgcn_mfma_f32_16x16x32_bf16(a[t], b[u], acc[t][u], 0, 0, 0);
        __syncthreads();
    }

    const int quad = lane >> 4, l15 = lane & 15;
    float bv[4];
#pragma unroll
    for (int u = 0; u < 4; u++)
        bv[u] = bias[(size_t)e * NN + n0 + wn * 64 + u * 16 + l15];
#pragma unroll
    for (int t = 0; t < 4; t++) {
#pragma unroll
        for (int rr = 0; rr < 4; rr++) {
            int row = wm * 64 + t * 16 + quad * 4 + rr;
            if (m0 + row < cnt) {
                int tok = toks[row];
#pragma unroll
                for (int u = 0; u < 4; u++) {
                    int col = n0 + wn * 64 + u * 16 + l15;
                    float v = acc[t][u][rr] + bv[u];
                    if (MODE == 0) {
                        v = fmaxf(v, 0.0f);
                        ((__hip_bfloat16*)Out)[(size_t)tok * NN + col] = __float2bfloat16(v);
                    } else {
                        ((float*)Out)[(size_t)tok * NN + col] = v;
                    }
                }
            }
        }
    }
}

extern "C" void kernel_launch(void* const* d_in, const int* in_sizes, int n_in,
                              void* d_out, int out_size, void* d_ws, size_t ws_size,
                              hipStream_t stream) {
    const float* x        = (const float*)d_in[0];
    const float* w_switch = (const float*)d_in[1];
    const float* b_switch = (const float*)d_in[2];
    const float* w1       = (const float*)d_in[3];
    const float* b1       = (const float*)d_in[4];
    const float* w2       = (const float*)d_in[5];
    const float* b2       = (const float*)d_in[6];

    float* out = (float*)d_out;
    float* out_tail = out + (size_t)NTOK * DDIM;

    char* ws = (char*)d_ws;
    __hip_bfloat16* xs = (__hip_bfloat16*)(ws);                        // 8 MB
    __hip_bfloat16* h  = (__hip_bfloat16*)(ws + 8388608ull);           // 32 MB
    __hip_bfloat16* wt = (__hip_bfloat16*)(ws + 41943040ull);          // 67.1 MB (shared w1t/w2t)
    int* bucket        = (int*)(ws + 109051904ull);                    // 128 KB
    int* amax_arr      = (int*)(ws + 109182976ull);                    // 16 KB
    float* partial     = (float*)(ws + 109199360ull);                  // 16 KB
    int* ecnt          = (int*)(ws + 109215744ull);                    // 32 B

    hipLaunchKernelGGL(route_kernel, dim3(256), dim3(256), 0, stream,
                       x, w_switch, b_switch, xs, amax_arr, partial);
    hipLaunchKernelGGL(finalize_kernel, dim3(1), dim3(256), 0, stream, partial, out_tail);
    hipLaunchKernelGGL(bucket_kernel, dim3(NEXP), dim3(1024), 0, stream,
                       amax_arr, bucket, ecnt);

    // w1 [E,1024,4096] -> w1t [E,4096,1024]
    hipLaunchKernelGGL((transpose_kernel<DDIM, FDIM>), dim3(FDIM / 64, DDIM / 64, NEXP),
                       dim3(256), 0, stream, w1, wt);
    hipLaunchKernelGGL((gemm_kernel<0, DDIM, FDIM>), dim3(FDIM / 128, 32, NEXP),
                       dim3(256), 0, stream, xs, wt, b1, bucket, ecnt, (void*)h);

    // w2 [E,4096,1024] -> w2t [E,1024,4096]  (reuses wt after gemm1)
    hipLaunchKernelGGL((transpose_kernel<FDIM, DDIM>), dim3(DDIM / 64, FDIM / 64, NEXP),
                       dim3(256), 0, stream, w2, wt);
    hipLaunchKernelGGL((gemm_kernel<1, FDIM, DDIM>), dim3(DDIM / 128, 32, NEXP),
                       dim3(256), 0, stream, h, wt, b2, bucket, ecnt, (void*)out);
}

// Round 4
// 529.537 us; speedup vs baseline: 2.3547x; 1.1146x over previous
//
#include <hip/hip_runtime.h>
#include <hip/hip_bf16.h>

#define NTOK 4096
#define DDIM 1024
#define NEXP 8
#define FDIM 4096
#define MAXTILES 40

typedef __attribute__((ext_vector_type(4))) float f32x4;
typedef __attribute__((ext_vector_type(8))) short bf16x8;
typedef __attribute__((ext_vector_type(8))) unsigned short u16x8;

#define GLDS(g, l) __builtin_amdgcn_global_load_lds( \
    (const __attribute__((address_space(1))) unsigned int*)(g), \
    (__attribute__((address_space(3))) unsigned int*)(l), 16, 0, 0)

// ---------------- route: no global atomics. Writes xs (bf16), amax[], partial[256][16] ----
__global__ __launch_bounds__(256) void route_kernel(
    const float* __restrict__ x,         // [NTOK, D]
    const float* __restrict__ w_switch,  // [D, E]
    const float* __restrict__ b_switch,  // [E]
    __hip_bfloat16* __restrict__ xs,     // [NTOK, D]
    int* __restrict__ amax_arr,          // [NTOK]
    float* __restrict__ partial)         // [256][16]: 0..7 prob sums, 8..15 counts
{
    const int tid = threadIdx.x;
    const int wave = tid >> 6, lane = tid & 63;
    __shared__ float pr[4][16];

    float wacc[16];
#pragma unroll
    for (int j = 0; j < 16; j++) wacc[j] = 0.0f;

    for (int i = 0; i < 4; i++) {
        const int n = blockIdx.x * 16 + wave * 4 + i;
        const float4* xr = (const float4*)(x + (size_t)n * DDIM);
        float4 xv[4];
#pragma unroll
        for (int j = 0; j < 4; j++) xv[j] = xr[lane + j * 64];

        float acc[NEXP];
#pragma unroll
        for (int e = 0; e < NEXP; e++) acc[e] = 0.0f;
#pragma unroll
        for (int j = 0; j < 4; j++) {
            const int dbase = (lane + j * 64) * 4;
#pragma unroll
            for (int c = 0; c < 4; c++) {
                const float4* wr = (const float4*)(w_switch + (size_t)(dbase + c) * NEXP);
                float4 w0 = wr[0], w1 = wr[1];
                float xvc = ((const float*)&xv[j])[c];
                acc[0] += xvc * w0.x; acc[1] += xvc * w0.y;
                acc[2] += xvc * w0.z; acc[3] += xvc * w0.w;
                acc[4] += xvc * w1.x; acc[5] += xvc * w1.y;
                acc[6] += xvc * w1.z; acc[7] += xvc * w1.w;
            }
        }
#pragma unroll
        for (int e = 0; e < NEXP; e++) {
            float v = acc[e];
#pragma unroll
            for (int off = 32; off > 0; off >>= 1) v += __shfl_xor(v, off, 64);
            acc[e] = v;
        }
        float mx = -1e30f;
#pragma unroll
        for (int e = 0; e < NEXP; e++) {
            acc[e] += b_switch[e];
            mx = fmaxf(mx, acc[e]);
        }
        float sum = 0.0f;
#pragma unroll
        for (int e = 0; e < NEXP; e++) { acc[e] = __expf(acc[e] - mx); sum += acc[e]; }
        float inv = 1.0f / sum;
        float pmax = -1.0f; int amax = 0;
#pragma unroll
        for (int e = 0; e < NEXP; e++) {
            float p = acc[e] * inv;
            acc[e] = p;
            if (p > pmax) { pmax = p; amax = e; }
        }
#pragma unroll
        for (int e = 0; e < NEXP; e++) {
            wacc[e] += acc[e];
            wacc[8 + e] += (amax == e) ? 1.0f : 0.0f;
        }
        if (lane == 0) amax_arr[n] = amax;
#pragma unroll
        for (int j = 0; j < 4; j++) {
            ushort4 pk;
            __hip_bfloat16* pp = (__hip_bfloat16*)&pk;
            pp[0] = __float2bfloat16(xv[j].x * pmax);
            pp[1] = __float2bfloat16(xv[j].y * pmax);
            pp[2] = __float2bfloat16(xv[j].z * pmax);
            pp[3] = __float2bfloat16(xv[j].w * pmax);
            *(ushort4*)(xs + (size_t)n * DDIM + (lane + j * 64) * 4) = pk;
        }
    }
    if (lane == 0) {
#pragma unroll
        for (int j = 0; j < 16; j++) pr[wave][j] = wacc[j];
    }
    __syncthreads();
    if (tid < 16)
        partial[blockIdx.x * 16 + tid] = pr[0][tid] + pr[1][tid] + pr[2][tid] + pr[3][tid];
}

// ---------------- bucket: per-expert token lists, ballot-aggregated, LDS counter ----------
__global__ __launch_bounds__(1024) void bucket_kernel(
    const int* __restrict__ amax_arr, int* __restrict__ bucket, int* __restrict__ ecnt)
{
    const int e = blockIdx.x;
    __shared__ int ctr;
    if (threadIdx.x == 0) ctr = 0;
    __syncthreads();
    const int lane = threadIdx.x & 63;
    for (int c = 0; c < NTOK; c += 1024) {
        int t = c + threadIdx.x;
        bool my = (amax_arr[t] == e);
        unsigned long long mask = __ballot(my);
        int cnt = __popcll(mask);
        int base = 0;
        if (lane == 0 && cnt) base = atomicAdd(&ctr, cnt);
        base = __shfl(base, 0, 64);
        if (my) {
            int rank = __popcll(mask & ((1ull << lane) - 1ull));
            bucket[e * NTOK + base + rank] = t;
        }
    }
    __syncthreads();
    if (threadIdx.x == 0) ecnt[e] = ctr;
}

// ---------------- finalize + m-tile table ----------------
__global__ __launch_bounds__(256) void finalize_table_kernel(
    const float* __restrict__ partial, const int* __restrict__ ecnt,
    float* __restrict__ out_tail, int* __restrict__ table)
{
    __shared__ float red[16][16];
    const int j = threadIdx.x & 15, g = threadIdx.x >> 4;
    float s = 0.0f;
    for (int k = 0; k < 16; k++) s += partial[(size_t)(g + k * 16) * 16 + j];
    red[g][j] = s;
    __syncthreads();
    if (threadIdx.x < 16) {
        float t = 0.0f;
        for (int k = 0; k < 16; k++) t += red[k][threadIdx.x];
        int dst = (threadIdx.x < 8) ? (8 + threadIdx.x) : (threadIdx.x - 8);
        out_tail[dst] = t;
    }
    if (threadIdx.x == 16) out_tail[16] = 0.0f;  // n_dropped
    if (threadIdx.x == 0) {
        int idx = 0;
        for (int e = 0; e < NEXP; e++) {
            int cnt = ecnt[e];
            for (int m0 = 0; m0 < cnt; m0 += 128) table[idx++] = (e << 16) | m0;
        }
        for (; idx < MAXTILES; idx++) table[idx] = -1;
    }
}

// ---------------- init_out: out[t][:] = b2[amax[t]][:] (bias pre-fill for atomic GEMM2) ----
__global__ __launch_bounds__(256) void init_out_kernel(
    const float* __restrict__ b2, const int* __restrict__ amax_arr,
    float* __restrict__ out)
{
    const int t = blockIdx.x;
    const int e = amax_arr[t];
    const float4* br = (const float4*)(b2 + (size_t)e * DDIM);
    ((float4*)(out + (size_t)t * DDIM))[threadIdx.x] = br[threadIdx.x];
}

// ---------------- transpose+convert: fp32 [E,R,C] -> bf16 [E,C,R] ----------------
template <int R, int C>
__global__ __launch_bounds__(256) void transpose_kernel(
    const float* __restrict__ in, __hip_bfloat16* __restrict__ outp)
{
    const int e = blockIdx.z;
    const int r0 = blockIdx.y * 64, c0 = blockIdx.x * 64;
    __shared__ __hip_bfloat16 t[64 * 65];
    const int tid = threadIdx.x;
    const int ri = tid >> 4, c4 = (tid & 15) * 4;
    const float* src = in + ((size_t)e * R + r0) * C + c0;
#pragma unroll
    for (int rr = 0; rr < 4; rr++) {
        int r = ri + rr * 16;
        float4 v = *(const float4*)(src + (size_t)r * C + c4);
        t[r * 65 + c4 + 0] = __float2bfloat16(v.x);
        t[r * 65 + c4 + 1] = __float2bfloat16(v.y);
        t[r * 65 + c4 + 2] = __float2bfloat16(v.z);
        t[r * 65 + c4 + 3] = __float2bfloat16(v.w);
    }
    __syncthreads();
    const int co = tid >> 2, m = tid & 3;
    u16x8 v0, v1;
#pragma unroll
    for (int idx = 0; idx < 8; idx++)
        ((unsigned short*)&v0)[idx] = *(const unsigned short*)&t[(m * 16 + idx) * 65 + co];
#pragma unroll
    for (int idx = 0; idx < 8; idx++)
        ((unsigned short*)&v1)[idx] = *(const unsigned short*)&t[(m * 16 + idx + 8) * 65 + co];
    __hip_bfloat16* dst = outp + ((size_t)e * C + c0 + co) * R + r0 + m * 16;
    *(u16x8*)(dst) = v0;
    *(u16x8*)(dst + 8) = v1;
}

// ---------------- grouped GEMM body: 128x128 tile, BK=32, global_load_lds ------
// MODE 0: h = bf16(relu(acc + bias)), KS=1.   MODE 1: unsafeAtomicAdd fp32 (bias pre-filled).
template <int MODE, int K, int NN, int KS>
__device__ __forceinline__ void gemm_body(
    const __hip_bfloat16* __restrict__ A,
    const __hip_bfloat16* __restrict__ Bt,
    const float* __restrict__ bias,
    const int* __restrict__ bucket,
    const int* __restrict__ ecnt,
    const int* __restrict__ table,
    void* __restrict__ Out)
{
    const int entry = table[blockIdx.y];
    if (entry < 0) return;
    const int e = entry >> 16;
    const int m0 = entry & 0xffff;
    const int cnt = ecnt[e];
    const int n0 = blockIdx.x * 128;
    const int kbase = (K / KS) * blockIdx.z;

    __shared__ __align__(16) __hip_bfloat16 Asm[128 * 32];
    __shared__ __align__(16) __hip_bfloat16 Bsm[128 * 32];
    __shared__ int toks[128];

    const int tid = threadIdx.x;
    if (tid < 128) {
        int r = m0 + tid;
        toks[tid] = bucket[e * NTOK + (r < cnt ? r : cnt - 1)];
    }
    __syncthreads();

    const int wave = tid >> 6, lane = tid & 63;
    const int r = lane & 15, kq = lane >> 4;
    const int g0 = 2 * wave, g1 = 2 * wave + 1;

    const __hip_bfloat16* pA0 = A + (size_t)toks[g0 * 16 + r] * K + kbase + kq * 8;
    const __hip_bfloat16* pA1 = A + (size_t)toks[g1 * 16 + r] * K + kbase + kq * 8;
    const __hip_bfloat16* pB0 = Bt + ((size_t)e * NN + n0 + g0 * 16 + r) * K + kbase + kq * 8;
    const __hip_bfloat16* pB1 = Bt + ((size_t)e * NN + n0 + g1 * 16 + r) * K + kbase + kq * 8;
    char* lA0 = (char*)Asm + g0 * 1024;
    char* lA1 = (char*)Asm + g1 * 1024;
    char* lB0 = (char*)Bsm + g0 * 1024;
    char* lB1 = (char*)Bsm + g1 * 1024;

    const int wm = wave & 1, wn = wave >> 1;
    f32x4 acc[4][4];
#pragma unroll
    for (int t = 0; t < 4; t++)
#pragma unroll
        for (int u = 0; u < 4; u++) acc[t][u] = (f32x4){0.f, 0.f, 0.f, 0.f};

    for (int k0 = 0; k0 < K / KS; k0 += 32) {
        GLDS(pA0, lA0); GLDS(pA1, lA1);
        GLDS(pB0, lB0); GLDS(pB1, lB1);
        pA0 += 32; pA1 += 32; pB0 += 32; pB1 += 32;
        __syncthreads();
        bf16x8 a[4], b[4];
#pragma unroll
        for (int t = 0; t < 4; t++)
            a[t] = *(const bf16x8*)((const char*)Asm + (wm * 4 + t) * 1024 + lane * 16);
#pragma unroll
        for (int u = 0; u < 4; u++)
            b[u] = *(const bf16x8*)((const char*)Bsm + (wn * 4 + u) * 1024 + lane * 16);
#pragma unroll
        for (int t = 0; t < 4; t++)
#pragma unroll
            for (int u = 0; u < 4; u++)
                acc[t][u] = __builtin_amdgcn_mfma_f32_16x16x32_bf16(a[t], b[u], acc[t][u], 0, 0, 0);
        __syncthreads();
    }

    const int quad = lane >> 4, l15 = lane & 15;
    float bv[4];
#pragma unroll
    for (int u = 0; u < 4; u++)
        bv[u] = (MODE == 0) ? bias[(size_t)e * NN + n0 + wn * 64 + u * 16 + l15] : 0.0f;
#pragma unroll
    for (int t = 0; t < 4; t++) {
#pragma unroll
        for (int rr = 0; rr < 4; rr++) {
            int row = wm * 64 + t * 16 + quad * 4 + rr;
            if (m0 + row < cnt) {
                int tok = toks[row];
#pragma unroll
                for (int u = 0; u < 4; u++) {
                    int col = n0 + wn * 64 + u * 16 + l15;
                    float v = acc[t][u][rr] + bv[u];
                    if (MODE == 0) {
                        v = fmaxf(v, 0.0f);
                        ((__hip_bfloat16*)Out)[(size_t)tok * NN + col] = __float2bfloat16(v);
                    } else {
                        unsafeAtomicAdd(&((float*)Out)[(size_t)tok * NN + col], v);
                    }
                }
            }
        }
    }
}

__global__ __launch_bounds__(256) void gemm_ffn1(
    const __hip_bfloat16* __restrict__ A, const __hip_bfloat16* __restrict__ Bt,
    const float* __restrict__ bias, const int* __restrict__ bucket,
    const int* __restrict__ ecnt, const int* __restrict__ table, void* __restrict__ Out)
{
    gemm_body<0, DDIM, FDIM, 1>(A, Bt, bias, bucket, ecnt, table, Out);
}

__global__ __launch_bounds__(256) void gemm_ffn2(
    const __hip_bfloat16* __restrict__ A, const __hip_bfloat16* __restrict__ Bt,
    const float* __restrict__ bias, const int* __restrict__ bucket,
    const int* __restrict__ ecnt, const int* __restrict__ table, void* __restrict__ Out)
{
    gemm_body<1, FDIM, DDIM, 2>(A, Bt, bias, bucket, ecnt, table, Out);
}

extern "C" void kernel_launch(void* const* d_in, const int* in_sizes, int n_in,
                              void* d_out, int out_size, void* d_ws, size_t ws_size,
                              hipStream_t stream) {
    const float* x        = (const float*)d_in[0];
    const float* w_switch = (const float*)d_in[1];
    const float* b_switch = (const float*)d_in[2];
    const float* w1       = (const float*)d_in[3];
    const float* b1       = (const float*)d_in[4];
    const float* w2       = (const float*)d_in[5];
    const float* b2       = (const float*)d_in[6];

    float* out = (float*)d_out;
    float* out_tail = out + (size_t)NTOK * DDIM;

    char* ws = (char*)d_ws;
    __hip_bfloat16* xs = (__hip_bfloat16*)(ws);                        // 8 MB
    __hip_bfloat16* h  = (__hip_bfloat16*)(ws + 8388608ull);           // 32 MB
    __hip_bfloat16* wt = (__hip_bfloat16*)(ws + 41943040ull);          // 64 MB (shared w1t/w2t)
    int* bucket        = (int*)(ws + 109051904ull);                    // 128 KB
    int* amax_arr      = (int*)(ws + 109182976ull);                    // 16 KB
    float* partial     = (float*)(ws + 109199360ull);                  // 16 KB
    int* ecnt          = (int*)(ws + 109215744ull);                    // 32 B
    int* table         = (int*)(ws + 109215776ull);                    // 160 B

    hipLaunchKernelGGL(route_kernel, dim3(256), dim3(256), 0, stream,
                       x, w_switch, b_switch, xs, amax_arr, partial);
    hipLaunchKernelGGL(bucket_kernel, dim3(NEXP), dim3(1024), 0, stream,
                       amax_arr, bucket, ecnt);
    hipLaunchKernelGGL(finalize_table_kernel, dim3(1), dim3(256), 0, stream,
                       partial, ecnt, out_tail, table);
    hipLaunchKernelGGL(init_out_kernel, dim3(NTOK), dim3(256), 0, stream,
                       b2, amax_arr, out);

    // w1 [E,1024,4096] -> w1t [E,4096,1024]
    hipLaunchKernelGGL((transpose_kernel<DDIM, FDIM>), dim3(FDIM / 64, DDIM / 64, NEXP),
                       dim3(256), 0, stream, w1, wt);
    hipLaunchKernelGGL(gemm_ffn1, dim3(FDIM / 128, MAXTILES), dim3(256), 0, stream,
                       xs, wt, b1, bucket, ecnt, table, (void*)h);

    // w2 [E,4096,1024] -> w2t [E,1024,4096]  (reuses wt after gemm1)
    hipLaunchKernelGGL((transpose_kernel<FDIM, DDIM>), dim3(DDIM / 64, FDIM / 64, NEXP),
                       dim3(256), 0, stream, w2, wt);
    hipLaunchKernelGGL(gemm_ffn2, dim3(DDIM / 128, MAXTILES, 2), dim3(256), 0, stream,
                       h, wt, b2, bucket, ecnt, table, (void*)out);
}